// Round 8
// baseline (232.880 us; speedup 1.0000x reference)
//
#include <hip/hip_runtime.h>
#include <hip/hip_bf16.h>
#include <cstdint>
#include <cstddef>

#define NN 4096

typedef float f32x4 __attribute__((ext_vector_type(4)));
typedef short s16x8 __attribute__((ext_vector_type(8)));

// ---------- prep: bit-plane mask maskT[chunk][d] (bit i = row sbase+i), deg counts ----------
__global__ __launch_bounds__(256) void k_prep(const float* __restrict__ K,
    unsigned* __restrict__ degc, unsigned long long* __restrict__ maskT) {
  const int lane = threadIdx.x & 63;
  const int wv = threadIdx.x >> 6;
  const int d0 = blockIdx.x * 256 + lane * 4;      // each lane owns 4 columns
  const int sbase = blockIdx.y * 256 + wv * 64;    // this wave's 64-row chunk
  const int chunk = blockIdx.y * 4 + wv;
  unsigned long long w0 = 0, w1 = 0, w2 = 0, w3 = 0;
#pragma unroll 8
  for (int i = 0; i < 64; ++i) {
    const float4 kv = *(const float4*)(K + (size_t)(sbase + i) * NN + d0);
    w0 |= ((unsigned long long)(kv.x != 0.0f)) << i;
    w1 |= ((unsigned long long)(kv.y != 0.0f)) << i;
    w2 |= ((unsigned long long)(kv.z != 0.0f)) << i;
    w3 |= ((unsigned long long)(kv.w != 0.0f)) << i;
  }
  unsigned long long* mp = maskT + (size_t)chunk * NN + d0;
  mp[0] = w0; mp[1] = w1; mp[2] = w2; mp[3] = w3;
  atomicAdd(&degc[d0 + 0], (unsigned)__popcll(w0));
  atomicAdd(&degc[d0 + 1], (unsigned)__popcll(w1));
  atomicAdd(&degc[d0 + 2], (unsigned)__popcll(w2));
  atomicAdd(&degc[d0 + 3], (unsigned)__popcll(w3));
}

// ---------- one-wave register Sinkhorn: lane=row, m[j]=col j; no barriers, no spills ----------
// 20 alternating LSE norms; transpose via stride-65 LDS (2-way bank alias = free).
// Ends (after odd # of transposes) with m[j] = logRes[j][lane]; also leaves
// lds[j*65+lane] = m[j], i.e. lds[r*65+c] = logRes[r][c].
__device__ __forceinline__ void sinkhorn_wave(float (&m)[64], float* lds, int lane) {
  for (int it = 0; it < 20; ++it) {
    float a0 = m[0], a1 = m[1], a2 = m[2], a3 = m[3];
#pragma unroll
    for (int j = 4; j < 64; j += 4) {
      a0 = fmaxf(a0, m[j]);     a1 = fmaxf(a1, m[j + 1]);
      a2 = fmaxf(a2, m[j + 2]); a3 = fmaxf(a3, m[j + 3]);
    }
    const float mx = fmaxf(fmaxf(a0, a1), fmaxf(a2, a3));
    float s0 = 0.f, s1 = 0.f, s2 = 0.f, s3 = 0.f;
#pragma unroll
    for (int j = 0; j < 64; j += 4) {
      s0 += __expf(m[j] - mx);     s1 += __expf(m[j + 1] - mx);
      s2 += __expf(m[j + 2] - mx); s3 += __expf(m[j + 3] - mx);
    }
    const float lse = mx + __logf((s0 + s1) + (s2 + s3));
#pragma unroll
    for (int j = 0; j < 64; ++j) m[j] -= lse;
    if (it < 19) {                       // transpose
#pragma unroll
      for (int j = 0; j < 64; ++j) lds[lane * 65 + j] = m[j];
      asm volatile("s_waitcnt lgkmcnt(0)" ::: "memory");
#pragma unroll
      for (int j = 0; j < 64; ++j) m[j] = lds[j * 65 + lane];
      asm volatile("" ::: "memory");
    }
  }
#pragma unroll
  for (int j = 0; j < 64; ++j) lds[j * 65 + lane] = m[j];   // lds[r*65+c] = log val
  asm volatile("s_waitcnt lgkmcnt(0)" ::: "memory");
}

// ---------- layer-0 transform ----------
__global__ __launch_bounds__(256) void k_xform0(const float* __restrict__ K,
    const unsigned* __restrict__ degc,
    const float* __restrict__ cw, const float* __restrict__ cb,
    const float* __restrict__ sw, const float* __restrict__ sb,
    __hip_bfloat16* __restrict__ gHi, __hip_bfloat16* __restrict__ gLo,
    float* __restrict__ xselfT) {
  const int lane = threadIdx.x & 63;
  const int wv = threadIdx.x >> 6;
  const int s = blockIdx.x * 64 + lane;
  const float xv = K[(size_t)s * NN + s];          // diag(K)
  const float ds = rsqrtf((float)degc[s]);
#pragma unroll
  for (int i = 0; i < 16; ++i) {
    const int c = wv * 16 + i;
    const float gv = ds * xv * cw[c];
    const __hip_bfloat16 hi = __float2bfloat16(gv);
    gHi[(size_t)c * NN + s] = hi;
    gLo[(size_t)c * NN + s] = __float2bfloat16(gv - __bfloat162float(hi));
    xselfT[(size_t)c * NN + s] = xv * sw[c] + sb[c] + cb[c];
  }
}

// ---------- fused [wave-0 sinkhorn(vT)] + layer transform (weights in LDS) ----------
// grid (64, 2): blockIdx.x = s-tile, blockIdx.y = 32-channel half.
__global__ __launch_bounds__(256, 1) void k_xform(const float* __restrict__ vT,
    const float* __restrict__ xoutT, const unsigned* __restrict__ degc,
    const float* __restrict__ cw, const float* __restrict__ cb,
    const float* __restrict__ sw, const float* __restrict__ sb,
    __hip_bfloat16* __restrict__ gHi, __hip_bfloat16* __restrict__ gLo,
    float* __restrict__ xselfT) {
  __shared__ float skl[64 * 65];
  __shared__ float xt[64][64];
  __shared__ float wcl[64 * 32], wsl[64 * 32];     // [k][c-local]
  const int tid = threadIdx.x;
  const int lane = tid & 63;
  const int wv = tid >> 6;
  const int s = blockIdx.x * 64 + lane;
  const int cbase = blockIdx.y * 32;
  if (wv == 0) {                                   // serial sinkhorn, reg-resident
    float m[64];
#pragma unroll
    for (int j = 0; j < 64; ++j) m[j] = vT[j * 64 + lane] * 20.0f;   // /tau, coalesced
    sinkhorn_wave(m, skl, lane);
  } else if (wv == 1) {                            // stage xt rows 0..31 (raw, no sk yet)
#pragma unroll
    for (int k = 0; k < 32; ++k) xt[k][lane] = xoutT[(size_t)k * NN + s];
  } else if (wv == 2) {                            // stage xt rows 32..63
#pragma unroll
    for (int k = 32; k < 64; ++k) xt[k][lane] = xoutT[(size_t)k * NN + s];
  } else {                                         // stage this block's weight halves
#pragma unroll
    for (int q = 0; q < 32; ++q) {
      const int e = q * 64 + lane;
      wcl[e] = cw[(e >> 5) * 64 + cbase + (e & 31)];
      wsl[e] = sw[(e >> 5) * 64 + cbase + (e & 31)];
    }
  }
  __syncthreads();
  const float skv = __expf(skl[blockIdx.x * 65 + lane]);   // sk[row=blk.x][col=lane]
#pragma unroll
  for (int i = 0; i < 16; ++i) xt[wv * 16 + i][lane] += skv;   // x = xout + sk
  __syncthreads();
  float accC[8], accS[8];
#pragma unroll
  for (int i = 0; i < 8; ++i) { accC[i] = 0.f; accS[i] = 0.f; }
  for (int k = 0; k < 64; ++k) {
    const float xv = xt[k][lane];
#pragma unroll
    for (int i = 0; i < 8; ++i) {
      accC[i] = fmaf(xv, wcl[k * 32 + wv * 8 + i], accC[i]);   // broadcast LDS read
      accS[i] = fmaf(xv, wsl[k * 32 + wv * 8 + i], accS[i]);
    }
  }
  const float ds = rsqrtf((float)degc[s]);
#pragma unroll
  for (int i = 0; i < 8; ++i) {
    const int c = cbase + wv * 8 + i;
    const float gv = ds * accC[i];
    const __hip_bfloat16 hi = __float2bfloat16(gv);
    gHi[(size_t)c * NN + s] = hi;
    gLo[(size_t)c * NN + s] = __float2bfloat16(gv - __bfloat162float(hi));
    xselfT[(size_t)c * NN + s] = accS[i] + sb[c] + cb[c];
  }
}

// ---------- MFMA masked aggregation, full K per block, in-block combine ----------
// Block handles 16 d's; 8 waves = 4 channel-tiles x 2 K-splits; writes vT (transposed).
__global__ __launch_bounds__(512) void k_agg(const unsigned long long* __restrict__ maskT,
    const __hip_bfloat16* __restrict__ gHi, const __hip_bfloat16* __restrict__ gLo,
    const float* __restrict__ xselfT, const unsigned* __restrict__ degc,
    const float* __restrict__ kw, const float* __restrict__ kb,
    float* __restrict__ xoutT, float* __restrict__ vT) {
  const int tid = threadIdx.x;
  const int lane = tid & 63;
  const int wv = tid >> 6;           // 0..7
  const int mtile = wv & 3;          // channel 16-group
  const int ks = wv >> 2;            // K-split 0/1
  const int l15 = lane & 15;
  const int h = lane >> 4;           // 0..3
  const int d = blockIdx.x * 16 + l15;
  const int ch = mtile * 16 + l15;   // A-operand row (channel)
  const short* __restrict__ gh = (const short*)gHi;
  const short* __restrict__ gl = (const short*)gLo;
  f32x4 acch = {0.f, 0.f, 0.f, 0.f};
  f32x4 accl = {0.f, 0.f, 0.f, 0.f};
  const int c0 = ks * 32;
#pragma unroll 4
  for (int c = c0; c < c0 + 32; ++c) {
    const unsigned long long w = maskT[(size_t)c * NN + d];
    const unsigned half0 = (unsigned)w, half1 = (unsigned)(w >> 32);
#pragma unroll
    for (int t = 0; t < 2; ++t) {
      const unsigned half = t ? half1 : half0;
      const unsigned hb = (half >> (8 * h)) & 0xFFu;
      s16x8 bfr;
#pragma unroll
      for (int j = 0; j < 8; ++j)
        bfr[j] = (short)(((hb >> j) & 1u) * 0x3F80u);   // bit -> bf16 1.0/0.0
      const size_t abase = (size_t)ch * NN + (size_t)(c * 64 + t * 32 + 8 * h);
      const s16x8 ah = *(const s16x8*)(gh + abase);
      const s16x8 al = *(const s16x8*)(gl + abase);
      acch = __builtin_amdgcn_mfma_f32_16x16x32_bf16(ah, bfr, acch, 0, 0, 0);
      accl = __builtin_amdgcn_mfma_f32_16x16x32_bf16(al, bfr, accl, 0, 0, 0);
    }
  }
  // ---- in-block K-split reduce + combine + cls partial ----
  __shared__ float rbuf[4][64][5];   // [mtile][lane][r] (pad 5: 2-way max)
  __shared__ float vred[16][17];
  f32x4 tot;
#pragma unroll
  for (int r = 0; r < 4; ++r) tot[r] = acch[r] + accl[r];
  if (ks == 1) {
#pragma unroll
    for (int r = 0; r < 4; ++r) rbuf[mtile][lane][r] = tot[r];
  }
  __syncthreads();
  if (ks == 0) {
    // C/D layout: col = lane&15 (=d), row = (lane>>4)*4 + reg (=channel in mtile)
    const float dd = rsqrtf((float)degc[d]);
    float p = 0.f;
#pragma unroll
    for (int r = 0; r < 4; ++r) {
      const int chr = mtile * 16 + h * 4 + r;
      const float xo = xselfT[(size_t)chr * NN + d] + dd * (tot[r] + rbuf[mtile][lane][r]);
      xoutT[(size_t)chr * NN + d] = xo;
      p = fmaf(xo, kw[chr], p);
    }
    vred[l15][mtile * 4 + h] = p;
  }
  __syncthreads();
  if (tid < 16) {
    float sum = kb[0];
#pragma unroll
    for (int q = 0; q < 16; ++q) sum += vred[tid][q];
    const int d2 = blockIdx.x * 16 + tid;
    vT[(d2 & 63) * 64 + (d2 >> 6)] = sum;          // transposed for coalesced sinkhorn load
  }
}

// ---------- fused [wave-0 sinkhorn(vT)] + final scores -> flat node-order ----------
__global__ __launch_bounds__(256, 1) void k_scores(const float* __restrict__ vT,
    const float* __restrict__ xoutT, const float* __restrict__ fw,
    const float* __restrict__ fb, float* __restrict__ scores) {
  __shared__ float skl[64 * 65];
  __shared__ float fwl[64];
  const int tid = threadIdx.x;
  const int lane = tid & 63;
  const int wv = tid >> 6;
  if (wv == 0) {
    float m[64];
#pragma unroll
    for (int j = 0; j < 64; ++j) m[j] = vT[j * 64 + lane] * 20.0f;
    sinkhorn_wave(m, skl, lane);
  } else if (wv == 1) {
    fwl[lane] = fw[lane];
  }
  __syncthreads();
  const int n = blockIdx.x * 256 + tid;
  const float skv = __expf(skl[(n >> 6) * 65 + (n & 63)]);
  float acc = 0.f, sumw = 0.f;
#pragma unroll 8
  for (int k = 0; k < 64; ++k) {
    const float w = fwl[k];                        // broadcast
    sumw += w;
    acc = fmaf(xoutT[(size_t)k * NN + n], w, acc);
  }
  scores[n] = acc + skv * sumw + fb[0];            // flat node order == coalesced for final
}

// ---------- final Sinkhorn: one wave; m[j]=scores[j*64+lane]=Smat[lane][j] ----------
__global__ __launch_bounds__(64, 1) void k_skfinal(const float* __restrict__ scores,
                                                   float* __restrict__ out) {
  __shared__ float lds[64 * 65];
  const int lane = threadIdx.x;
  float m[64];
#pragma unroll
  for (int j = 0; j < 64; ++j) m[j] = scores[j * 64 + lane] * 20.0f;   // coalesced
  sinkhorn_wave(m, lds, lane);
  // final layout: m[j] = logRes[j][lane]  -> coalesced store
#pragma unroll
  for (int j = 0; j < 64; ++j) out[j * 64 + lane] = __expf(m[j]);
}

extern "C" void kernel_launch(void* const* d_in, const int* in_sizes, int n_in,
                              void* d_out, int out_size, void* d_ws, size_t ws_size,
                              hipStream_t stream) {
  const float* K = (const float*)d_in[0];
  const float* cw[3] = {(const float*)d_in[4],  (const float*)d_in[10], (const float*)d_in[16]};
  const float* cb[3] = {(const float*)d_in[5],  (const float*)d_in[11], (const float*)d_in[17]};
  const float* sw[3] = {(const float*)d_in[6],  (const float*)d_in[12], (const float*)d_in[18]};
  const float* sb[3] = {(const float*)d_in[7],  (const float*)d_in[13], (const float*)d_in[19]};
  const float* kw[3] = {(const float*)d_in[8],  (const float*)d_in[14], (const float*)d_in[20]};
  const float* kb[3] = {(const float*)d_in[9],  (const float*)d_in[15], (const float*)d_in[21]};
  const float* fw = (const float*)d_in[22];
  const float* fb = (const float*)d_in[23];
  float* out = (float*)d_out;

  char* ws = (char*)d_ws;
  const size_t KB = 1024, MB = 1024 * 1024;
  unsigned* degc            = (unsigned*)(ws + 0);                // 16 KB
  float* vT                 = (float*)(ws + 32 * KB);             // 16 KB
  float* scores             = (float*)(ws + 48 * KB);             // 16 KB
  unsigned long long* maskT = (unsigned long long*)(ws + 64 * KB);// 2 MB
  __hip_bfloat16* gHi       = (__hip_bfloat16*)(ws + 64 * KB + 2 * MB);            // 512 KB
  __hip_bfloat16* gLo       = (__hip_bfloat16*)(ws + 64 * KB + 2 * MB + 512 * KB); // 512 KB
  float* xselfT             = (float*)(ws + 64 * KB + 3 * MB);    // 1 MB
  float* xoutT              = (float*)(ws + 64 * KB + 4 * MB);    // 1 MB
  (void)in_sizes; (void)n_in; (void)out_size; (void)ws_size;

  hipMemsetAsync(degc, 0, NN * sizeof(unsigned), stream);
  k_prep<<<dim3(16, 16), 256, 0, stream>>>(K, degc, maskT);

  k_xform0<<<64, 256, 0, stream>>>(K, degc, cw[0], cb[0], sw[0], sb[0], gHi, gLo, xselfT);
  k_agg<<<256, 512, 0, stream>>>(maskT, gHi, gLo, xselfT, degc, kw[0], kb[0], xoutT, vT);
  for (int l = 1; l < 3; ++l) {
    k_xform<<<dim3(64, 2), 256, 0, stream>>>(vT, xoutT, degc, cw[l], cb[l], sw[l], sb[l],
                                             gHi, gLo, xselfT);
    k_agg<<<256, 512, 0, stream>>>(maskT, gHi, gLo, xselfT, degc, kw[l], kb[l], xoutT, vT);
  }
  k_scores<<<16, 256, 0, stream>>>(vT, xoutT, fw, fb, scores);
  k_skfinal<<<1, 64, 0, stream>>>(scores, out);
}